// Round 1
// baseline (2324.357 us; speedup 1.0000x reference)
//
#include <hip/hip_runtime.h>
#include <math.h>

#define B_  32
#define S_  2048
#define DQ  1024
#define DV  1024
#define U_  1024

// ---------------- K0: t[b,u] = b1[u] + b2[u]; zero context output ----------
__global__ void init_kernel(const float* __restrict__ b1, const float* __restrict__ b2,
                            float* __restrict__ t, float* __restrict__ ctx) {
    int i = blockIdx.x * 256 + threadIdx.x;   // 32768 total = B_*U_ = B_*DV
    int u = i & (U_ - 1);
    t[i]   = b1[u] + b2[u];
    ctx[i] = 0.f;
}

// ---------------- K1: t[b,u] += query[b,:] @ W2[:,u]  (k-split partials) ----
__global__ void projq_kernel(const float* __restrict__ q, const float* __restrict__ W2,
                             float* __restrict__ t) {
    int b  = blockIdx.x;       // 32
    int ks = blockIdx.y;       // 4 chunks of 256 along d
    int tid = threadIdx.x;     // 256
    __shared__ float qs[256];
    qs[tid] = q[b * DQ + ks * 256 + tid];
    __syncthreads();
    float a0 = 0.f, a1 = 0.f, a2 = 0.f, a3 = 0.f;
    const float* w = W2 + (size_t)(ks * 256) * U_;
    for (int d = 0; d < 256; ++d) {
        float qd = qs[d];
        const float* wr = w + (size_t)d * U_ + tid;
        a0 += qd * wr[0];
        a1 += qd * wr[256];
        a2 += qd * wr[512];
        a3 += qd * wr[768];
    }
    atomicAdd(&t[b * U_ + tid      ], a0);
    atomicAdd(&t[b * U_ + tid + 256], a1);
    atomicAdd(&t[b * U_ + tid + 512], a2);
    atomicAdd(&t[b * U_ + tid + 768], a3);
}

// ---------------- K2: fused scores GEMM --------------------------------------
// score[b,s] = sum_u tanh( values[b,s,:]@W1[:,u] + t[b,u] ) * V[u]
// Block tile: 128 rows (s) x 64 cols (u), K staged in chunks of 16.
#define MT 128
#define NT 64
#define KT 16
#define SA_LD 132   // MT + 4 pad (keeps float4 alignment)
#define SB_LD 68    // NT + 4 pad

__launch_bounds__(256, 2)
__global__ void scores_kernel(const float* __restrict__ values, const float* __restrict__ W1,
                              const float* __restrict__ t, const float* __restrict__ V,
                              float* __restrict__ scores) {
    __shared__ float sA[KT][SA_LD];   // sA[k][m] = values row m, col k0+k
    __shared__ float sB[KT][SB_LD];   // sB[k][j] = W1[k0+k][u0+j]
    __shared__ float fscore[MT];

    const int b   = blockIdx.y;
    const int s0  = blockIdx.x * MT;
    const int tid = threadIdx.x;
    const int tx  = tid & 15;   // n direction (16)
    const int ty  = tid >> 4;   // m direction (16)

    if (tid < MT) fscore[tid] = 0.f;

    const float* vbase = values + ((size_t)b * S_ + s0) * (size_t)DV;

    const int lm  = tid >> 2;          // 0..63 : row for A-staging
    const int lkq = (tid & 3) * 4;     // 0,4,8,12 : k quad for A-staging
    const int lbk = tid >> 4;          // 0..15 : k for B-staging
    const int lbj = (tid & 15) * 4;    // 0..60 : u quad for B-staging

    for (int nt = 0; nt < U_ / NT; ++nt) {
        const int u0 = nt * NT;
        float acc[8][4];
#pragma unroll
        for (int i = 0; i < 8; ++i)
#pragma unroll
            for (int j = 0; j < 4; ++j) acc[i][j] = 0.f;

        for (int k0 = 0; k0 < DV; k0 += KT) {
            __syncthreads();
            // stage A: 128 rows x 16 k (each thread: 2 rows x 4 k via float4)
            {
                const float4 v0 = *(const float4*)(vbase + (size_t)lm * DV + k0 + lkq);
                const float4 v1 = *(const float4*)(vbase + (size_t)(lm + 64) * DV + k0 + lkq);
                sA[lkq + 0][lm] = v0.x; sA[lkq + 1][lm] = v0.y;
                sA[lkq + 2][lm] = v0.z; sA[lkq + 3][lm] = v0.w;
                sA[lkq + 0][lm + 64] = v1.x; sA[lkq + 1][lm + 64] = v1.y;
                sA[lkq + 2][lm + 64] = v1.z; sA[lkq + 3][lm + 64] = v1.w;
            }
            // stage B: 16 k x 64 u (each thread one float4)
            {
                *(float4*)&sB[lbk][lbj] =
                    *(const float4*)(W1 + (size_t)(k0 + lbk) * U_ + u0 + lbj);
            }
            __syncthreads();
#pragma unroll
            for (int k = 0; k < KT; ++k) {
                float4 va0 = *(const float4*)&sA[k][ty * 8];
                float4 va1 = *(const float4*)&sA[k][ty * 8 + 4];
                float4 vb  = *(const float4*)&sB[k][tx * 4];
                float a_[8] = {va0.x, va0.y, va0.z, va0.w, va1.x, va1.y, va1.z, va1.w};
                float b_[4] = {vb.x, vb.y, vb.z, vb.w};
#pragma unroll
                for (int i = 0; i < 8; ++i)
#pragma unroll
                    for (int j = 0; j < 4; ++j) acc[i][j] += a_[i] * b_[j];
            }
        }

        // epilogue: tanh + dot with V, reduce over n (tx), accumulate fscore[m]
        float tq[4], vv[4];
#pragma unroll
        for (int j = 0; j < 4; ++j) {
            int u = u0 + tx * 4 + j;
            tq[j] = t[b * U_ + u];
            vv[j] = V[u];
        }
#pragma unroll
        for (int i = 0; i < 8; ++i) {
            float p = 0.f;
#pragma unroll
            for (int j = 0; j < 4; ++j) p += tanhf(acc[i][j] + tq[j]) * vv[j];
            p += __shfl_down(p, 8, 16);
            p += __shfl_down(p, 4, 16);
            p += __shfl_down(p, 2, 16);
            p += __shfl_down(p, 1, 16);
            if (tx == 0) fscore[ty * 8 + i] += p;   // unique writer per m
        }
    }
    __syncthreads();
    if (tid < MT) scores[(size_t)b * S_ + s0 + tid] = fscore[tid];
}

// ---------------- K3: softmax over S per batch ------------------------------
__global__ void softmax_kernel(const float* __restrict__ scores, float* __restrict__ wout) {
    int b = blockIdx.x;
    int tid = threadIdx.x;   // 256
    __shared__ float red[256];
    float v[8];
    float m = -1e30f;
#pragma unroll
    for (int i = 0; i < 8; ++i) {
        v[i] = scores[(size_t)b * S_ + tid + i * 256];
        m = fmaxf(m, v[i]);
    }
    red[tid] = m; __syncthreads();
    for (int off = 128; off > 0; off >>= 1) {
        if (tid < off) red[tid] = fmaxf(red[tid], red[tid + off]);
        __syncthreads();
    }
    m = red[0];
    __syncthreads();
    float s = 0.f;
#pragma unroll
    for (int i = 0; i < 8; ++i) { v[i] = __expf(v[i] - m); s += v[i]; }
    red[tid] = s; __syncthreads();
    for (int off = 128; off > 0; off >>= 1) {
        if (tid < off) red[tid] += red[tid + off];
        __syncthreads();
    }
    float inv = 1.f / red[0];
#pragma unroll
    for (int i = 0; i < 8; ++i) wout[(size_t)b * S_ + tid + i * 256] = v[i] * inv;
}

// ---------------- K4: context[b,d] = sum_s w[b,s] * values[b,s,d] -----------
__global__ void context_kernel(const float* __restrict__ values, const float* __restrict__ w,
                               float* __restrict__ ctx) {
    int b  = blockIdx.x;   // 32
    int dc = blockIdx.y;   // 4 chunks of 256 d
    int sc = blockIdx.z;   // 8 chunks of 256 s
    int tid = threadIdx.x; // 256
    int d = dc * 256 + tid;
    __shared__ float ws_[256];
    ws_[tid] = w[(size_t)b * S_ + sc * 256 + tid];
    __syncthreads();
    float acc = 0.f;
    const float* vp = values + ((size_t)b * S_ + sc * 256) * (size_t)DV + d;
#pragma unroll 4
    for (int s = 0; s < 256; ++s) acc += ws_[s] * vp[(size_t)s * DV];
    atomicAdd(&ctx[b * DV + d], acc);
}

// ---------------- launch ----------------------------------------------------
extern "C" void kernel_launch(void* const* d_in, const int* in_sizes, int n_in,
                              void* d_out, int out_size, void* d_ws, size_t ws_size,
                              hipStream_t stream) {
    const float* query  = (const float*)d_in[0];
    const float* values = (const float*)d_in[1];
    const float* W1     = (const float*)d_in[2];
    const float* b1     = (const float*)d_in[3];
    const float* W2     = (const float*)d_in[4];
    const float* b2     = (const float*)d_in[5];
    const float* V      = (const float*)d_in[6];
    // bV (d_in[7]) shifts all scores equally -> softmax-invariant; outputs unaffected.

    float* out  = (float*)d_out;
    float* ctx  = out;                 // [32, 1024] context_vector (output 0)
    float* wout = out + B_ * DV;       // [32, 2048] attention_weights (output 1)

    float* t      = (float*)d_ws;      // [32, 1024] proj_q + b1 + b2
    float* scores = t + B_ * U_;       // [32, 2048]

    init_kernel   <<<dim3(128),       256, 0, stream>>>(b1, b2, t, ctx);
    projq_kernel  <<<dim3(32, 4),     256, 0, stream>>>(query, W2, t);
    scores_kernel <<<dim3(16, 32),    256, 0, stream>>>(values, W1, t, V, scores);
    softmax_kernel<<<dim3(32),        256, 0, stream>>>(scores, wout);
    context_kernel<<<dim3(32, 4, 8),  256, 0, stream>>>(values, wout, ctx);
}

// Round 3
// 637.071 us; speedup vs baseline: 3.6485x; 3.6485x over previous
//
#include <hip/hip_runtime.h>
#include <math.h>

#define B_  32
#define S_  2048
#define DV  1024
#define U_  1024

typedef __attribute__((ext_vector_type(8))) short bf16x8;
typedef __attribute__((ext_vector_type(4))) float f32x4;

__device__ inline unsigned short f2bf(float f) {
    unsigned int x = __float_as_uint(f);
    return (unsigned short)((x + 0x7fffu + ((x >> 16) & 1u)) >> 16);
}

__device__ inline float tanh_fast(float x) {
    float ax = fabsf(x);
    float e  = __expf(ax + ax);
    float t  = 1.0f - __fdividef(2.0f, e + 1.0f);
    return copysignf(t, x);
}

// ---------------- K0: t[b,u] = b1[u]+b2[u]; zero ctx + scores ---------------
__global__ void init_kernel(const float* __restrict__ b1, const float* __restrict__ b2,
                            float* __restrict__ t, float* __restrict__ ctx,
                            float* __restrict__ scores) {
    int i = blockIdx.x * 256 + threadIdx.x;   // 65536
    scores[i] = 0.f;
    if (i < B_ * U_) {
        int u = i & (U_ - 1);
        t[i]   = b1[u] + b2[u];
        ctx[i] = 0.f;
    }
}

// ---------------- K1: t[b,u] += query[b,:] @ W2[:,u] ------------------------
__global__ void projq_kernel(const float* __restrict__ q, const float* __restrict__ W2,
                             float* __restrict__ t) {
    int b  = blockIdx.x;
    int ks = blockIdx.y;
    int tid = threadIdx.x;
    __shared__ float qs[256];
    qs[tid] = q[b * DV + ks * 256 + tid];
    __syncthreads();
    float a0 = 0.f, a1 = 0.f, a2 = 0.f, a3 = 0.f;
    const float* w = W2 + (size_t)(ks * 256) * U_;
    for (int d = 0; d < 256; ++d) {
        float qd = qs[d];
        const float* wr = w + (size_t)d * U_ + tid;
        a0 += qd * wr[0];
        a1 += qd * wr[256];
        a2 += qd * wr[512];
        a3 += qd * wr[768];
    }
    atomicAdd(&t[b * U_ + tid      ], a0);
    atomicAdd(&t[b * U_ + tid + 256], a1);
    atomicAdd(&t[b * U_ + tid + 512], a2);
    atomicAdd(&t[b * U_ + tid + 768], a3);
}

// ---------------- prep: values fp32 -> bf16 ---------------------------------
// B_*S_*DV = 67,108,864 elems; 8/thread -> 32768 blocks of 256. (R2 bug: 16384)
__global__ void cvt_values(const float* __restrict__ v, unsigned short* __restrict__ o) {
    size_t i = ((size_t)blockIdx.x * 256 + threadIdx.x) * 8;
    float4 f0 = *(const float4*)(v + i);
    float4 f1 = *(const float4*)(v + i + 4);
    union { unsigned short s[8]; uint4 u; } p;
    p.s[0] = f2bf(f0.x); p.s[1] = f2bf(f0.y); p.s[2] = f2bf(f0.z); p.s[3] = f2bf(f0.w);
    p.s[4] = f2bf(f1.x); p.s[5] = f2bf(f1.y); p.s[6] = f2bf(f1.z); p.s[7] = f2bf(f1.w);
    *(uint4*)(o + i) = p.u;
}

// ---------------- prep: W1 [k][u] fp32 -> W1T [u][k] bf16 -------------------
__global__ void prep_w1t(const float* __restrict__ W1, unsigned short* __restrict__ W1T) {
    __shared__ float tile[64][65];
    int k0 = blockIdx.x * 64, u0 = blockIdx.y * 64;
    int t = threadIdx.x;
    int lr = t >> 4, lc = (t & 15) * 4;
#pragma unroll
    for (int i = 0; i < 4; ++i) {
        float4 f = *(const float4*)&W1[(size_t)(k0 + lr + i * 16) * U_ + u0 + lc];
        tile[lr + i * 16][lc + 0] = f.x; tile[lr + i * 16][lc + 1] = f.y;
        tile[lr + i * 16][lc + 2] = f.z; tile[lr + i * 16][lc + 3] = f.w;
    }
    __syncthreads();
    int ur = t >> 2, kq = (t & 3) * 16;
    union { unsigned short s[8]; uint4 u; } p0, p1;
#pragma unroll
    for (int e = 0; e < 8; ++e) p0.s[e] = f2bf(tile[kq + e][ur]);
#pragma unroll
    for (int e = 0; e < 8; ++e) p1.s[e] = f2bf(tile[kq + 8 + e][ur]);
    unsigned short* dst = W1T + (size_t)(u0 + ur) * 1024 + k0 + kq;
    *(uint4*)dst       = p0.u;
    *(uint4*)(dst + 8) = p1.u;
}

// ---------------- K2: MFMA scores GEMM + fused tanh/V epilogue --------------
// Block: 128 rows (s) x 256 cols (u), 256 thr = 4 waves (2x2), wave 64x128.
// Grid 512 s-tiles x 4 u-tiles; partial scores via global atomicAdd.
template<bool ABF16>
__launch_bounds__(256, 2)
__global__ void scores_mfma(const void* __restrict__ aPtr,
                            const unsigned short* __restrict__ W1T,
                            const float* __restrict__ t,
                            const float* __restrict__ V,
                            float* __restrict__ scores) {
    __shared__ unsigned short sA[128 * 40];   // pad 40: frag reads 2-way (free)
    __shared__ unsigned short sB[256 * 40];
    __shared__ float fscore[128];

    const int tid  = threadIdx.x;
    const int lane = tid & 63;
    const int wave = tid >> 6;
    const int wm = wave & 1, wn = wave >> 1;
    const int l15 = lane & 15, lq = lane >> 4;

    // XCD swizzle: 4 blocks sharing an A-strip get ids {x, x+8, x+16, x+24}
    const int id    = blockIdx.x;
    const int utile = (id >> 3) & 3;
    const int stile = (id & 7) | ((id >> 5) << 3);
    const size_t row0 = (size_t)stile * 128;
    const int b       = (int)(row0 >> 11);
    const int s_local = (int)(row0 & 2047);
    const int u0      = utile * 256;

    if (tid < 128) fscore[tid] = 0.f;

    const int ar = tid >> 1, ak = (tid & 1) << 4;   // A stage: row, k-offset
    const int br = tid >> 1, bk = (tid & 1) << 4;   // B stage

    const float* Af = (const float*)aPtr + (row0 + ar) * 1024 + ak;
    const unsigned short* Ab = (const unsigned short*)aPtr + (row0 + ar) * 1024 + ak;
    const unsigned short* Bp0 = W1T + (size_t)(u0 + br) * 1024 + bk;
    const unsigned short* Bp1 = Bp0 + 128 * 1024;

    f32x4 acc[4][8];
#pragma unroll
    for (int i = 0; i < 4; ++i)
#pragma unroll
        for (int j = 0; j < 8; ++j) acc[i][j] = (f32x4)0.f;

    uint4 sa0, sa1, sb0, sb1, sb2, sb3;
    float4 fa0, fa1, fa2, fa3;

    // preload k-step 0
    if (ABF16) {
        sa0 = *(const uint4*)(Ab);
        sa1 = *(const uint4*)(Ab + 8);
    } else {
        fa0 = *(const float4*)(Af);
        fa1 = *(const float4*)(Af + 4);
        fa2 = *(const float4*)(Af + 8);
        fa3 = *(const float4*)(Af + 12);
    }
    sb0 = *(const uint4*)(Bp0);
    sb1 = *(const uint4*)(Bp0 + 8);
    sb2 = *(const uint4*)(Bp1);
    sb3 = *(const uint4*)(Bp1 + 8);

    for (int k0 = 0; k0 < 1024; k0 += 32) {
        __syncthreads();
        // commit staged regs -> LDS
        if (ABF16) {
            *(uint4*)&sA[ar * 40 + ak]     = sa0;
            *(uint4*)&sA[ar * 40 + ak + 8] = sa1;
        } else {
            union { unsigned short s[8]; uint4 u; } p0, p1;
            p0.s[0] = f2bf(fa0.x); p0.s[1] = f2bf(fa0.y); p0.s[2] = f2bf(fa0.z); p0.s[3] = f2bf(fa0.w);
            p0.s[4] = f2bf(fa1.x); p0.s[5] = f2bf(fa1.y); p0.s[6] = f2bf(fa1.z); p0.s[7] = f2bf(fa1.w);
            p1.s[0] = f2bf(fa2.x); p1.s[1] = f2bf(fa2.y); p1.s[2] = f2bf(fa2.z); p1.s[3] = f2bf(fa2.w);
            p1.s[4] = f2bf(fa3.x); p1.s[5] = f2bf(fa3.y); p1.s[6] = f2bf(fa3.z); p1.s[7] = f2bf(fa3.w);
            *(uint4*)&sA[ar * 40 + ak]     = p0.u;
            *(uint4*)&sA[ar * 40 + ak + 8] = p1.u;
        }
        *(uint4*)&sB[br * 40 + bk]           = sb0;
        *(uint4*)&sB[br * 40 + bk + 8]       = sb1;
        *(uint4*)&sB[(br + 128) * 40 + bk]     = sb2;
        *(uint4*)&sB[(br + 128) * 40 + bk + 8] = sb3;

        // prefetch next k-step globals (overlap with MFMA below)
        if (k0 + 32 < 1024) {
            int nk = k0 + 32;
            if (ABF16) {
                sa0 = *(const uint4*)(Ab + nk);
                sa1 = *(const uint4*)(Ab + nk + 8);
            } else {
                fa0 = *(const float4*)(Af + nk);
                fa1 = *(const float4*)(Af + nk + 4);
                fa2 = *(const float4*)(Af + nk + 8);
                fa3 = *(const float4*)(Af + nk + 12);
            }
            sb0 = *(const uint4*)(Bp0 + nk);
            sb1 = *(const uint4*)(Bp0 + nk + 8);
            sb2 = *(const uint4*)(Bp1 + nk);
            sb3 = *(const uint4*)(Bp1 + nk + 8);
        }
        __syncthreads();

        bf16x8 af[4];
#pragma unroll
        for (int i = 0; i < 4; ++i)
            af[i] = *(const bf16x8*)&sA[(64 * wm + 16 * i + l15) * 40 + lq * 8];
#pragma unroll
        for (int j = 0; j < 8; ++j) {
            bf16x8 bfj = *(const bf16x8*)&sB[(128 * wn + 16 * j + l15) * 40 + lq * 8];
#pragma unroll
            for (int i = 0; i < 4; ++i)
                acc[i][j] = __builtin_amdgcn_mfma_f32_16x16x32_bf16(af[i], bfj, acc[i][j], 0, 0, 0);
        }
    }

    // epilogue: score[m] += sum_u tanh(P + t[b,u]) * V[u]
    float tu[8], vu[8];
#pragma unroll
    for (int j = 0; j < 8; ++j) {
        int u = u0 + 128 * wn + 16 * j + l15;
        tu[j] = t[b * U_ + u];
        vu[j] = V[u];
    }
#pragma unroll
    for (int i = 0; i < 4; ++i) {
#pragma unroll
        for (int r = 0; r < 4; ++r) {
            float p = 0.f;
#pragma unroll
            for (int j = 0; j < 8; ++j) p += tanh_fast(acc[i][j][r] + tu[j]) * vu[j];
            p += __shfl_xor(p, 1);
            p += __shfl_xor(p, 2);
            p += __shfl_xor(p, 4);
            p += __shfl_xor(p, 8);
            if (l15 == 0) atomicAdd(&fscore[64 * wm + 16 * i + lq * 4 + r], p);
        }
    }
    __syncthreads();
    if (tid < 128) atomicAdd(&scores[(size_t)b * S_ + s_local + tid], fscore[tid]);
}

// ---------------- K2-low: fp32 vector scores (last-resort ws fallback) ------
__launch_bounds__(256, 2)
__global__ void scores_vec(const float* __restrict__ values, const float* __restrict__ W1,
                           const float* __restrict__ t, const float* __restrict__ V,
                           float* __restrict__ scores) {
    __shared__ float vA[16][132];
    __shared__ float vB[16][68];
    __shared__ float fscore[128];
    const int b   = blockIdx.y;
    const int s0  = blockIdx.x * 128;
    const int tid = threadIdx.x;
    const int tx  = tid & 15, ty = tid >> 4;
    if (tid < 128) fscore[tid] = 0.f;
    const float* vbase = values + ((size_t)b * S_ + s0) * (size_t)DV;
    const int lm = tid >> 2, lkq = (tid & 3) * 4;
    const int lbk = tid >> 4, lbj = (tid & 15) * 4;
    for (int nt = 0; nt < U_ / 64; ++nt) {
        const int u0 = nt * 64;
        float acc[8][4];
#pragma unroll
        for (int i = 0; i < 8; ++i)
#pragma unroll
            for (int j = 0; j < 4; ++j) acc[i][j] = 0.f;
        for (int k0 = 0; k0 < DV; k0 += 16) {
            __syncthreads();
            const float4 v0 = *(const float4*)(vbase + (size_t)lm * DV + k0 + lkq);
            const float4 v1 = *(const float4*)(vbase + (size_t)(lm + 64) * DV + k0 + lkq);
            vA[lkq + 0][lm] = v0.x; vA[lkq + 1][lm] = v0.y;
            vA[lkq + 2][lm] = v0.z; vA[lkq + 3][lm] = v0.w;
            vA[lkq + 0][lm + 64] = v1.x; vA[lkq + 1][lm + 64] = v1.y;
            vA[lkq + 2][lm + 64] = v1.z; vA[lkq + 3][lm + 64] = v1.w;
            *(float4*)&vB[lbk][lbj] = *(const float4*)(W1 + (size_t)(k0 + lbk) * U_ + u0 + lbj);
            __syncthreads();
#pragma unroll
            for (int k = 0; k < 16; ++k) {
                float4 va0 = *(const float4*)&vA[k][ty * 8];
                float4 va1 = *(const float4*)&vA[k][ty * 8 + 4];
                float4 vb  = *(const float4*)&vB[k][tx * 4];
                float a_[8] = {va0.x, va0.y, va0.z, va0.w, va1.x, va1.y, va1.z, va1.w};
                float b_[4] = {vb.x, vb.y, vb.z, vb.w};
#pragma unroll
                for (int i = 0; i < 8; ++i)
#pragma unroll
                    for (int j = 0; j < 4; ++j) acc[i][j] += a_[i] * b_[j];
            }
        }
        float tq[4], vv[4];
#pragma unroll
        for (int j = 0; j < 4; ++j) {
            int u = u0 + tx * 4 + j;
            tq[j] = t[b * U_ + u];
            vv[j] = V[u];
        }
#pragma unroll
        for (int i = 0; i < 8; ++i) {
            float p = 0.f;
#pragma unroll
            for (int j = 0; j < 4; ++j) p += tanhf(acc[i][j] + tq[j]) * vv[j];
            p += __shfl_down(p, 8, 16);
            p += __shfl_down(p, 4, 16);
            p += __shfl_down(p, 2, 16);
            p += __shfl_down(p, 1, 16);
            if (tx == 0) fscore[ty * 8 + i] += p;
        }
    }
    __syncthreads();
    if (tid < 128) scores[(size_t)b * S_ + s0 + tid] = fscore[tid];
}

// ---------------- K3: softmax over S per batch ------------------------------
__global__ void softmax_kernel(const float* __restrict__ scores, float* __restrict__ wout) {
    int b = blockIdx.x;
    int tid = threadIdx.x;
    __shared__ float red[256];
    float v[8];
    float m = -1e30f;
#pragma unroll
    for (int i = 0; i < 8; ++i) {
        v[i] = scores[(size_t)b * S_ + tid + i * 256];
        m = fmaxf(m, v[i]);
    }
    red[tid] = m; __syncthreads();
    for (int off = 128; off > 0; off >>= 1) {
        if (tid < off) red[tid] = fmaxf(red[tid], red[tid + off]);
        __syncthreads();
    }
    m = red[0];
    __syncthreads();
    float s = 0.f;
#pragma unroll
    for (int i = 0; i < 8; ++i) { v[i] = __expf(v[i] - m); s += v[i]; }
    red[tid] = s; __syncthreads();
    for (int off = 128; off > 0; off >>= 1) {
        if (tid < off) red[tid] += red[tid + off];
        __syncthreads();
    }
    float inv = 1.f / red[0];
#pragma unroll
    for (int i = 0; i < 8; ++i) wout[(size_t)b * S_ + tid + i * 256] = v[i] * inv;
}

// ---------------- K4: context[b,d] = sum_s w[b,s] * values[b,s,d] -----------
__global__ void context_kernel(const float* __restrict__ values, const float* __restrict__ w,
                               float* __restrict__ ctx) {
    int b  = blockIdx.x;
    int dc = blockIdx.y;
    int sc = blockIdx.z;
    int tid = threadIdx.x;
    int d = dc * 256 + tid;
    __shared__ float ws_[256];
    ws_[tid] = w[(size_t)b * S_ + sc * 256 + tid];
    __syncthreads();
    float acc = 0.f;
    const float* vp = values + ((size_t)b * S_ + sc * 256) * (size_t)DV + d;
#pragma unroll 4
    for (int s = 0; s < 256; ++s) acc += ws_[s] * vp[(size_t)s * DV];
    atomicAdd(&ctx[b * DV + d], acc);
}

// ---------------- launch ----------------------------------------------------
extern "C" void kernel_launch(void* const* d_in, const int* in_sizes, int n_in,
                              void* d_out, int out_size, void* d_ws, size_t ws_size,
                              hipStream_t stream) {
    const float* query  = (const float*)d_in[0];
    const float* values = (const float*)d_in[1];
    const float* W1     = (const float*)d_in[2];
    const float* b1     = (const float*)d_in[3];
    const float* W2     = (const float*)d_in[4];
    const float* b2     = (const float*)d_in[5];
    const float* V      = (const float*)d_in[6];
    // bV (d_in[7]) shifts all scores equally -> softmax-invariant.

    float* out  = (float*)d_out;
    float* ctx  = out;                 // [32, 1024]
    float* wout = out + B_ * DV;       // [32, 2048]

    char* ws = (char*)d_ws;
    const size_t W1T_BYTES = (size_t)U_ * DV * 2;              // 2 MB
    const size_t T_BYTES   = (size_t)B_ * U_ * 4;              // 128 KB
    const size_t SC_BYTES  = (size_t)B_ * S_ * 4;              // 256 KB
    const size_t ABF_BYTES = (size_t)B_ * S_ * DV * 2;         // 128 MB

    if (ws_size >= W1T_BYTES + T_BYTES + SC_BYTES + ABF_BYTES) {
        // fast path: bf16 A + bf16 W1T, MFMA
        unsigned short* W1T = (unsigned short*)ws;
        float* t      = (float*)(ws + W1T_BYTES);
        float* scores = t + B_ * U_;
        unsigned short* Abf = (unsigned short*)(scores + B_ * S_);

        init_kernel   <<<dim3(256),      256, 0, stream>>>(b1, b2, t, ctx, scores);
        projq_kernel  <<<dim3(32, 4),    256, 0, stream>>>(query, W2, t);
        cvt_values    <<<dim3(32768),    256, 0, stream>>>(values, Abf);
        prep_w1t      <<<dim3(16, 16),   256, 0, stream>>>(W1, W1T);
        scores_mfma<true><<<dim3(2048),  256, 0, stream>>>(Abf, W1T, t, V, scores);
        softmax_kernel<<<dim3(32),       256, 0, stream>>>(scores, wout);
        context_kernel<<<dim3(32, 4, 8), 256, 0, stream>>>(values, wout, ctx);
    } else if (ws_size >= W1T_BYTES + T_BYTES + SC_BYTES) {
        // mid path: fp32 A converted in-kernel, bf16 W1T, MFMA
        unsigned short* W1T = (unsigned short*)ws;
        float* t      = (float*)(ws + W1T_BYTES);
        float* scores = t + B_ * U_;

        init_kernel   <<<dim3(256),      256, 0, stream>>>(b1, b2, t, ctx, scores);
        projq_kernel  <<<dim3(32, 4),    256, 0, stream>>>(query, W2, t);
        prep_w1t      <<<dim3(16, 16),   256, 0, stream>>>(W1, W1T);
        scores_mfma<false><<<dim3(2048), 256, 0, stream>>>(values, W1T, t, V, scores);
        softmax_kernel<<<dim3(32),       256, 0, stream>>>(scores, wout);
        context_kernel<<<dim3(32, 4, 8), 256, 0, stream>>>(values, wout, ctx);
    } else {
        // low path: round-1 fp32 vector kernel (384 KB ws, proven)
        float* t      = (float*)ws;
        float* scores = t + B_ * U_;

        init_kernel   <<<dim3(256),      256, 0, stream>>>(b1, b2, t, ctx, scores);
        projq_kernel  <<<dim3(32, 4),    256, 0, stream>>>(query, W2, t);
        scores_vec    <<<dim3(16, 32),   256, 0, stream>>>(values, W1, t, V, scores);
        softmax_kernel<<<dim3(32),       256, 0, stream>>>(scores, wout);
        context_kernel<<<dim3(32, 4, 8), 256, 0, stream>>>(values, wout, ctx);
    }
}